// Round 2
// baseline (826.906 us; speedup 1.0000x reference)
//
#include <hip/hip_runtime.h>
#include <cstdint>

// GRU recurrent autoencoder, MI355X persistent-MFMA implementation, round 2.
// B=2048, T=128, X=38, H=128, 3H=384. fp32 I/O, fp16 MFMA operands,
// fp32 accumulation + fp32 recurrent state (in registers).
//
// Round-2 changes vs round 1:
//  * Decoder feedback folded: gi = h @ W2 + b2 with W2 = Wih·linW (fp32
//    precompute in-kernel, fp16 frags). Decoder now has ONE barrier/step,
//    no o-buffer, and the output projection runs overlapped in the next
//    step from the same A-frags (plus a tail projection after the loop).
//  * Epilogue + h-write exec-masked to quad<2 (valid batch rows 0..7).
//  * r/z gates accumulate gi+gh in a single accumulator (bias-folded).

#define T_SEQ 128
#define X_DIM 38
#define H_DIM 128
#define B_TOT 2048
#define BT    8
#define HS    136   // h-state row stride in halfs
#define XSR   40    // x stage row stride in halfs (cols 38,39 stay zero)

typedef _Float16 half8 __attribute__((ext_vector_type(8)));
typedef float    f32x4 __attribute__((ext_vector_type(4)));

__device__ __forceinline__ float fast_sigmoid(float x) {
    return __builtin_amdgcn_rcpf(1.0f + __expf(-x));
}
__device__ __forceinline__ float fast_tanh(float x) {
    return 1.0f - 2.0f * __builtin_amdgcn_rcpf(1.0f + __expf(2.0f * x));
}

__global__ __launch_bounds__(512, 2)
void rae_gru_kernel(const float* __restrict__ x,
                    const float* __restrict__ eWih, const float* __restrict__ eWhh,
                    const float* __restrict__ ebih, const float* __restrict__ ebhh,
                    const float* __restrict__ dWih, const float* __restrict__ dWhh,
                    const float* __restrict__ dbih, const float* __restrict__ dbhh,
                    const float* __restrict__ linW, const float* __restrict__ linb,
                    float* __restrict__ out)
{
    __shared__ _Float16 hbuf[2 * 16 * HS];       // 8704 B, double-buffered h
    __shared__ _Float16 sbuf[2 * 8 * XSR];       // 1280 B, x stage
    __shared__ _Float16 w2lds[H_DIM * H_DIM];    // 32 KB, W2 fold staging (per gate)

    const int tid  = threadIdx.x;
    const int wv   = tid >> 6;
    const int ln   = tid & 63;
    const int quad = ln >> 4;
    const int mrow = ln & 15;
    const int b0   = blockIdx.x * BT;
    const int xr   = mrow & 7;
    const bool lower = (quad < 2);   // acc rows 0..7 = the valid batch rows

    for (int i = tid; i < 2 * 16 * HS; i += 512) hbuf[i] = (_Float16)0.0f;
    for (int i = tid; i < 2 * 8 * XSR; i += 512) sbuf[i] = (_Float16)0.0f;
    if (ln < X_DIM)
        sbuf[wv * XSR + ln] = (_Float16)x[((size_t)(b0 + wv) * T_SEQ) * X_DIM + ln];
    __syncthreads();

    // ---- persistent weight fragments ----
    half8 wh[3][4];   // Whh frags (K=128), per gate
    half8 wx[3][4];   // enc: Wih frags (chunks 0,1); dec: fused W2 (all 4)
    const int jcol[3] = { wv * 16 + mrow,
                          H_DIM + wv * 16 + mrow,
                          2 * H_DIM + wv * 16 + mrow };
    float b_r, b_z, b_ngi, b_ngh;

    // encoder weights
    {
        #pragma unroll
        for (int p = 0; p < 3; ++p) {
            const float* wr = eWhh + (size_t)jcol[p] * H_DIM;
            #pragma unroll
            for (int c = 0; c < 4; ++c) {
                const int kb = c * 32 + quad * 8;
                half8 v;
                #pragma unroll
                for (int e = 0; e < 8; ++e) v[e] = (_Float16)wr[kb + e];
                wh[p][c] = v;
            }
            const float* wir = eWih + (size_t)jcol[p] * X_DIM;
            #pragma unroll
            for (int c = 0; c < 2; ++c) {
                const int kb = c * 32 + quad * 8;
                half8 v;
                #pragma unroll
                for (int e = 0; e < 8; ++e) {
                    const int k = kb + e;
                    v[e] = (k < X_DIM) ? (_Float16)wir[k] : (_Float16)0.0f;
                }
                wx[p][c] = v;
            }
        }
        b_r  = ebih[jcol[0]] + ebhh[jcol[0]];
        b_z  = ebih[jcol[1]] + ebhh[jcol[1]];
        b_ngi = ebih[jcol[2]];
        b_ngh = ebhh[jcol[2]];
    }

    float hold[4] = {0.0f, 0.0f, 0.0f, 0.0f};

    auto epilogue = [&](const f32x4& ar, const f32x4& az,
                        const f32x4& agin, const f32x4& aghn,
                        _Float16* __restrict__ hwr) {
        if (lower) {   // upper half-wave (rows 8..15) is batch padding
            #pragma unroll
            for (int i = 0; i < 4; ++i) {
                const float r = fast_sigmoid(ar[i]);
                const float z = fast_sigmoid(az[i]);
                const float n = fast_tanh(agin[i] + r * aghn[i]);
                const float h = n + z * (hold[i] - n);
                hold[i] = h;
                hwr[(quad * 4 + i) * HS + wv * 16 + mrow] = (_Float16)h;
            }
        }
    };

    // ================= encoder (1 barrier/step) =================
    #pragma unroll 1
    for (int t = 0; t < T_SEQ; ++t) {
        float xnext = 0.0f;
        const bool pf = (t + 1 < T_SEQ) && (ln < X_DIM);
        if (pf) xnext = x[((size_t)(b0 + wv) * T_SEQ + (t + 1)) * X_DIM + ln];

        const _Float16* hrd = hbuf + (t & 1) * (16 * HS);
        _Float16*       hwr = hbuf + ((t & 1) ^ 1) * (16 * HS);
        const _Float16* sb  = sbuf + (t & 1) * (8 * XSR);

        half8 ha[4];
        #pragma unroll
        for (int c = 0; c < 4; ++c)
            ha[c] = *(const half8*)&hrd[mrow * HS + c * 32 + quad * 8];
        half8 xa0 = *(const half8*)&sb[xr * XSR + quad * 8];
        half8 xa1;
        #pragma unroll
        for (int e = 0; e < 8; ++e) xa1[e] = (_Float16)0.0f;
        if (quad == 0) xa1 = *(const half8*)&sb[xr * XSR + 32];

        f32x4 ar = { b_r, b_r, b_r, b_r };
        #pragma unroll
        for (int c = 0; c < 4; ++c)
            ar = __builtin_amdgcn_mfma_f32_16x16x32_f16(ha[c], wh[0][c], ar, 0, 0, 0);
        ar = __builtin_amdgcn_mfma_f32_16x16x32_f16(xa0, wx[0][0], ar, 0, 0, 0);
        ar = __builtin_amdgcn_mfma_f32_16x16x32_f16(xa1, wx[0][1], ar, 0, 0, 0);

        f32x4 az = { b_z, b_z, b_z, b_z };
        #pragma unroll
        for (int c = 0; c < 4; ++c)
            az = __builtin_amdgcn_mfma_f32_16x16x32_f16(ha[c], wh[1][c], az, 0, 0, 0);
        az = __builtin_amdgcn_mfma_f32_16x16x32_f16(xa0, wx[1][0], az, 0, 0, 0);
        az = __builtin_amdgcn_mfma_f32_16x16x32_f16(xa1, wx[1][1], az, 0, 0, 0);

        f32x4 aghn = { b_ngh, b_ngh, b_ngh, b_ngh };
        #pragma unroll
        for (int c = 0; c < 4; ++c)
            aghn = __builtin_amdgcn_mfma_f32_16x16x32_f16(ha[c], wh[2][c], aghn, 0, 0, 0);
        f32x4 agin = { b_ngi, b_ngi, b_ngi, b_ngi };
        agin = __builtin_amdgcn_mfma_f32_16x16x32_f16(xa0, wx[2][0], agin, 0, 0, 0);
        agin = __builtin_amdgcn_mfma_f32_16x16x32_f16(xa1, wx[2][1], agin, 0, 0, 0);

        epilogue(ar, az, agin, aghn, hwr);

        if (pf) sbuf[((t + 1) & 1) * (8 * XSR) + wv * XSR + ln] = (_Float16)xnext;
        __syncthreads();
    }

    // ================= decoder weight prep =================
    // wh <- dWhh frags
    {
        #pragma unroll
        for (int p = 0; p < 3; ++p) {
            const float* wr = dWhh + (size_t)jcol[p] * H_DIM;
            #pragma unroll
            for (int c = 0; c < 4; ++c) {
                const int kb = c * 32 + quad * 8;
                half8 v;
                #pragma unroll
                for (int e = 0; e < 8; ++e) v[e] = (_Float16)wr[kb + e];
                wh[p][c] = v;
            }
        }
    }
    // wx <- fused W2[j][k] = sum_m dWih[j][m] * linW[m][k], one gate per round.
    // Lane owns column kk; j is wave-uniform -> scalar loads for dWih rows.
    {
        const int kk = ((wv & 1) << 6) | ln;      // 0..127
        float lc[X_DIM];
        #pragma unroll
        for (int m = 0; m < X_DIM; ++m) lc[m] = linW[m * H_DIM + kk];  // coalesced

        #pragma unroll 1
        for (int p = 0; p < 3; ++p) {
            const int jb = (wv >> 1) * 32;        // 4 wave-pairs x 32 rows = 128
            #pragma unroll 1
            for (int jj = 0; jj < 32; ++jj) {
                const int j = __builtin_amdgcn_readfirstlane(jb + jj);
                const float* dwr = dWih + (size_t)(p * H_DIM + j) * X_DIM;
                float s = 0.0f;
                #pragma unroll
                for (int m = 0; m < X_DIM; ++m) s += dwr[m] * lc[m];
                w2lds[j * H_DIM + kk] = (_Float16)s;
            }
            __syncthreads();
            #pragma unroll
            for (int c = 0; c < 4; ++c)
                wx[p][c] = *(const half8*)&w2lds[(wv * 16 + mrow) * H_DIM + c * 32 + quad * 8];
            __syncthreads();
        }
    }
    // linear head frags + biases
    half8 wl[4];
    float lb = 0.0f;
    {
        const int n  = wv * 16 + mrow;
        const bool nv = (wv < 3) && (n < X_DIM);
        const float* lr = linW + (size_t)(nv ? n : 0) * H_DIM;
        #pragma unroll
        for (int c = 0; c < 4; ++c) {
            const int kb = c * 32 + quad * 8;
            half8 v;
            #pragma unroll
            for (int e = 0; e < 8; ++e)
                v[e] = nv ? (_Float16)lr[kb + e] : (_Float16)0.0f;
            wl[c] = v;
        }
        if (nv) lb = linb[n];
    }
    float b_r0, b_z0, b_ngi0;
    {
        float bf[3];
        #pragma unroll
        for (int p = 0; p < 3; ++p) {
            const float* dwr = dWih + (size_t)jcol[p] * X_DIM;
            float s = 0.0f;
            #pragma unroll
            for (int m = 0; m < X_DIM; ++m) s += linb[m] * dwr[m];
            bf[p] = s;
        }
        b_r0  = dbih[jcol[0]] + dbhh[jcol[0]];
        b_z0  = dbih[jcol[1]] + dbhh[jcol[1]];
        b_ngi0 = dbih[jcol[2]];
        b_ngh = dbhh[jcol[2]];
        b_r  = b_r0 + bf[0];
        b_z  = b_z0 + bf[1];
        b_ngi = b_ngi0 + bf[2];
    }

    // ================= decoder (1 barrier/step) =================
    #pragma unroll 1
    for (int t = 0; t < T_SEQ; ++t) {
        const _Float16* hrd = hbuf + (t & 1) * (16 * HS);
        _Float16*       hwr = hbuf + ((t & 1) ^ 1) * (16 * HS);

        half8 ha[4];
        #pragma unroll
        for (int c = 0; c < 4; ++c)
            ha[c] = *(const half8*)&hrd[mrow * HS + c * 32 + quad * 8];

        // overlapped output projection: o_{t-1} = d_t @ linW^T + lb
        if (wv < 3 && t > 0) {
            f32x4 al = { lb, lb, lb, lb };
            #pragma unroll
            for (int c = 0; c < 4; ++c)
                al = __builtin_amdgcn_mfma_f32_16x16x32_f16(ha[c], wl[c], al, 0, 0, 0);
            const int n = wv * 16 + mrow;
            if (lower && n < X_DIM) {
                #pragma unroll
                for (int i = 0; i < 4; ++i)
                    out[((size_t)(b0 + quad * 4 + i) * T_SEQ + (t - 1)) * X_DIM + n] = al[i];
            }
        }

        const float cr = t ? b_r : b_r0;
        const float cz = t ? b_z : b_z0;
        const float cn = t ? b_ngi : b_ngi0;

        f32x4 ar = { cr, cr, cr, cr };
        #pragma unroll
        for (int c = 0; c < 4; ++c)
            ar = __builtin_amdgcn_mfma_f32_16x16x32_f16(ha[c], wh[0][c], ar, 0, 0, 0);
        f32x4 az = { cz, cz, cz, cz };
        #pragma unroll
        for (int c = 0; c < 4; ++c)
            az = __builtin_amdgcn_mfma_f32_16x16x32_f16(ha[c], wh[1][c], az, 0, 0, 0);
        f32x4 aghn = { b_ngh, b_ngh, b_ngh, b_ngh };
        #pragma unroll
        for (int c = 0; c < 4; ++c)
            aghn = __builtin_amdgcn_mfma_f32_16x16x32_f16(ha[c], wh[2][c], aghn, 0, 0, 0);
        f32x4 agin = { cn, cn, cn, cn };
        if (t > 0) {   // t=0 feedback input is GO=0: gi = bias only
            #pragma unroll
            for (int c = 0; c < 4; ++c) {
                ar   = __builtin_amdgcn_mfma_f32_16x16x32_f16(ha[c], wx[0][c], ar, 0, 0, 0);
                az   = __builtin_amdgcn_mfma_f32_16x16x32_f16(ha[c], wx[1][c], az, 0, 0, 0);
                agin = __builtin_amdgcn_mfma_f32_16x16x32_f16(ha[c], wx[2][c], agin, 0, 0, 0);
            }
        }

        epilogue(ar, az, agin, aghn, hwr);
        __syncthreads();
    }

    // tail projection: o_{T-1} = d_T @ linW^T + lb  (d_T is in hbuf[0], T even)
    if (wv < 3) {
        const _Float16* hrd = hbuf;
        half8 ha[4];
        #pragma unroll
        for (int c = 0; c < 4; ++c)
            ha[c] = *(const half8*)&hrd[mrow * HS + c * 32 + quad * 8];
        f32x4 al = { lb, lb, lb, lb };
        #pragma unroll
        for (int c = 0; c < 4; ++c)
            al = __builtin_amdgcn_mfma_f32_16x16x32_f16(ha[c], wl[c], al, 0, 0, 0);
        const int n = wv * 16 + mrow;
        if (lower && n < X_DIM) {
            #pragma unroll
            for (int i = 0; i < 4; ++i)
                out[((size_t)(b0 + quad * 4 + i) * T_SEQ + (T_SEQ - 1)) * X_DIM + n] = al[i];
        }
    }
}

extern "C" void kernel_launch(void* const* d_in, const int* in_sizes, int n_in,
                              void* d_out, int out_size, void* d_ws, size_t ws_size,
                              hipStream_t stream) {
    (void)in_sizes; (void)n_in; (void)d_ws; (void)ws_size; (void)out_size;
    const float* x    = (const float*)d_in[0];
    const float* eWih = (const float*)d_in[1];
    const float* eWhh = (const float*)d_in[2];
    const float* ebih = (const float*)d_in[3];
    const float* ebhh = (const float*)d_in[4];
    const float* dWih = (const float*)d_in[5];
    const float* dWhh = (const float*)d_in[6];
    const float* dbih = (const float*)d_in[7];
    const float* dbhh = (const float*)d_in[8];
    const float* linW = (const float*)d_in[9];
    const float* linb = (const float*)d_in[10];
    float* out = (float*)d_out;

    rae_gru_kernel<<<dim3(B_TOT / BT), dim3(512), 0, stream>>>(
        x, eWih, eWhh, ebih, ebhh, dWih, dWhh, dbih, dbhh, linW, linb, out);
}

// Round 3
// 366.516 us; speedup vs baseline: 2.2561x; 2.2561x over previous
//
#include <hip/hip_runtime.h>
#include <cstdint>

// GRU recurrent autoencoder, MI355X persistent-MFMA implementation, round 3.
// B=2048, T=128, X=38, H=128, 3H=384. fp32 I/O, fp16 MFMA operands,
// fp32 accumulation + fp32 recurrent state (in registers).
//
// Round-3 changes vs round 2 (which spilled: runtime-indexed wx[p][c] in the
// prep loop demoted the frag array to scratch -> +52 MB HBM writes):
//  * r/z gates use a COMBINED weight Wc = dWhh + dWih*linW (fp32 sum in LDS,
//    one fp16 cast). Decoder weights: wh 48 + wxn 16 + wl 16 = 80 VGPRs.
//  * Decoder t=0 runs as a dedicated pre-step (gi = bias) while wh still
//    holds pure dWhh, before wh[0]/wh[1] are overwritten with combined frags.
//  * Every register-array access is compile-time-indexed (prep is three
//    explicit per-gate blocks).
//  * Decoder loop: 20 MFMAs/step, 1 barrier/step, projection overlapped.

#define T_SEQ 128
#define X_DIM 38
#define H_DIM 128
#define B_TOT 2048
#define BT    8
#define HS    136   // h-state row stride in halfs
#define XSR   40    // x stage row stride in halfs (cols 38,39 stay zero)

typedef _Float16 half8 __attribute__((ext_vector_type(8)));
typedef float    f32x4 __attribute__((ext_vector_type(4)));

__device__ __forceinline__ float fast_sigmoid(float x) {
    return __builtin_amdgcn_rcpf(1.0f + __expf(-x));
}
__device__ __forceinline__ float fast_tanh(float x) {
    return 1.0f - 2.0f * __builtin_amdgcn_rcpf(1.0f + __expf(2.0f * x));
}

__global__ __launch_bounds__(512, 2)
void rae_gru_kernel(const float* __restrict__ x,
                    const float* __restrict__ eWih, const float* __restrict__ eWhh,
                    const float* __restrict__ ebih, const float* __restrict__ ebhh,
                    const float* __restrict__ dWih, const float* __restrict__ dWhh,
                    const float* __restrict__ dbih, const float* __restrict__ dbhh,
                    const float* __restrict__ linW, const float* __restrict__ linb,
                    float* __restrict__ out)
{
    __shared__ _Float16 hbuf[2 * 16 * HS];       // 8704 B, double-buffered h
    __shared__ _Float16 sbuf[2 * 8 * XSR];       // 1280 B, x stage
    __shared__ _Float16 w2lds[H_DIM * H_DIM];    // 32 KB, weight-fold staging

    const int tid  = threadIdx.x;
    const int wv   = tid >> 6;
    const int ln   = tid & 63;
    const int quad = ln >> 4;
    const int mrow = ln & 15;
    const int b0   = blockIdx.x * BT;
    const int xr   = mrow & 7;
    const bool lower = (quad < 2);   // acc rows 0..7 = the valid batch rows

    for (int i = tid; i < 2 * 16 * HS; i += 512) hbuf[i] = (_Float16)0.0f;
    for (int i = tid; i < 2 * 8 * XSR; i += 512) sbuf[i] = (_Float16)0.0f;
    if (ln < X_DIM)
        sbuf[wv * XSR + ln] = (_Float16)x[((size_t)(b0 + wv) * T_SEQ) * X_DIM + ln];
    __syncthreads();

    // ---- persistent weight fragments (all accesses constant-indexed) ----
    half8 wh[3][4];    // enc: eWhh | dec: r/z = dWhh+W2 combined, n = pure dWhh
    half8 wxe[3][2];   // encoder Wih frags (dead after encoder phase)
    half8 wxn[4];      // decoder n-gate W2 frags
    half8 wl[4];       // linear head frags
    const int jcol[3] = { wv * 16 + mrow,
                          H_DIM + wv * 16 + mrow,
                          2 * H_DIM + wv * 16 + mrow };
    float b_r, b_z, b_ngi, b_ngh;

    // ---- encoder weights ----
    {
        #pragma unroll
        for (int p = 0; p < 3; ++p) {
            const float* wr = eWhh + (size_t)jcol[p] * H_DIM;
            #pragma unroll
            for (int c = 0; c < 4; ++c) {
                const int kb = c * 32 + quad * 8;
                half8 v;
                #pragma unroll
                for (int e = 0; e < 8; ++e) v[e] = (_Float16)wr[kb + e];
                wh[p][c] = v;
            }
            const float* wir = eWih + (size_t)jcol[p] * X_DIM;
            #pragma unroll
            for (int c = 0; c < 2; ++c) {
                const int kb = c * 32 + quad * 8;
                half8 v;
                #pragma unroll
                for (int e = 0; e < 8; ++e) {
                    const int k = kb + e;
                    v[e] = (k < X_DIM) ? (_Float16)wir[k] : (_Float16)0.0f;
                }
                wxe[p][c] = v;
            }
        }
        b_r  = ebih[jcol[0]] + ebhh[jcol[0]];
        b_z  = ebih[jcol[1]] + ebhh[jcol[1]];
        b_ngi = ebih[jcol[2]];
        b_ngh = ebhh[jcol[2]];
    }

    float hold[4] = {0.0f, 0.0f, 0.0f, 0.0f};

    auto epilogue = [&](const f32x4& ar, const f32x4& az,
                        const f32x4& agin, const f32x4& aghn,
                        _Float16* __restrict__ hwr) {
        if (lower) {   // upper half-wave (rows 8..15) is batch padding
            #pragma unroll
            for (int i = 0; i < 4; ++i) {
                const float r = fast_sigmoid(ar[i]);
                const float z = fast_sigmoid(az[i]);
                const float n = fast_tanh(agin[i] + r * aghn[i]);
                const float h = n + z * (hold[i] - n);
                hold[i] = h;
                hwr[(quad * 4 + i) * HS + wv * 16 + mrow] = (_Float16)h;
            }
        }
    };

    // ================= encoder (1 barrier/step) =================
    #pragma unroll 1
    for (int t = 0; t < T_SEQ; ++t) {
        float xnext = 0.0f;
        const bool pf = (t + 1 < T_SEQ) && (ln < X_DIM);
        if (pf) xnext = x[((size_t)(b0 + wv) * T_SEQ + (t + 1)) * X_DIM + ln];

        const _Float16* hrd = hbuf + (t & 1) * (16 * HS);
        _Float16*       hwr = hbuf + ((t & 1) ^ 1) * (16 * HS);
        const _Float16* sb  = sbuf + (t & 1) * (8 * XSR);

        half8 ha[4];
        #pragma unroll
        for (int c = 0; c < 4; ++c)
            ha[c] = *(const half8*)&hrd[mrow * HS + c * 32 + quad * 8];
        half8 xa0 = *(const half8*)&sb[xr * XSR + quad * 8];
        half8 xa1;
        #pragma unroll
        for (int e = 0; e < 8; ++e) xa1[e] = (_Float16)0.0f;
        if (quad == 0) xa1 = *(const half8*)&sb[xr * XSR + 32];

        f32x4 ar = { b_r, b_r, b_r, b_r };
        #pragma unroll
        for (int c = 0; c < 4; ++c)
            ar = __builtin_amdgcn_mfma_f32_16x16x32_f16(ha[c], wh[0][c], ar, 0, 0, 0);
        ar = __builtin_amdgcn_mfma_f32_16x16x32_f16(xa0, wxe[0][0], ar, 0, 0, 0);
        ar = __builtin_amdgcn_mfma_f32_16x16x32_f16(xa1, wxe[0][1], ar, 0, 0, 0);

        f32x4 az = { b_z, b_z, b_z, b_z };
        #pragma unroll
        for (int c = 0; c < 4; ++c)
            az = __builtin_amdgcn_mfma_f32_16x16x32_f16(ha[c], wh[1][c], az, 0, 0, 0);
        az = __builtin_amdgcn_mfma_f32_16x16x32_f16(xa0, wxe[1][0], az, 0, 0, 0);
        az = __builtin_amdgcn_mfma_f32_16x16x32_f16(xa1, wxe[1][1], az, 0, 0, 0);

        f32x4 aghn = { b_ngh, b_ngh, b_ngh, b_ngh };
        #pragma unroll
        for (int c = 0; c < 4; ++c)
            aghn = __builtin_amdgcn_mfma_f32_16x16x32_f16(ha[c], wh[2][c], aghn, 0, 0, 0);
        f32x4 agin = { b_ngi, b_ngi, b_ngi, b_ngi };
        agin = __builtin_amdgcn_mfma_f32_16x16x32_f16(xa0, wxe[2][0], agin, 0, 0, 0);
        agin = __builtin_amdgcn_mfma_f32_16x16x32_f16(xa1, wxe[2][1], agin, 0, 0, 0);

        epilogue(ar, az, agin, aghn, hwr);

        if (pf) sbuf[((t + 1) & 1) * (8 * XSR) + wv * XSR + ln] = (_Float16)xnext;
        __syncthreads();
    }

    // ================= decoder weight prep =================
    // Step A: pure dWhh frags (needed for the t=0 pre-step and the n gate).
    #pragma unroll
    for (int p = 0; p < 3; ++p) {
        const float* wr = dWhh + (size_t)jcol[p] * H_DIM;
        #pragma unroll
        for (int c = 0; c < 4; ++c) {
            const int kb = c * 32 + quad * 8;
            half8 v;
            #pragma unroll
            for (int e = 0; e < 8; ++e) v[e] = (_Float16)wr[kb + e];
            wh[p][c] = v;
        }
    }
    const float c_r0 = dbih[jcol[0]] + dbhh[jcol[0]];
    const float c_z0 = dbih[jcol[1]] + dbhh[jcol[1]];
    const float c_n0 = dbih[jcol[2]];
    b_ngh = dbhh[jcol[2]];

    // Step B: t=0 pre-step. d_1 = GRU(h_enc, o=0): gi = bias only.
    // h_enc is in hbuf[0] (T_SEQ even); write d_1 into hbuf[1].
    {
        const _Float16* hrd = hbuf;
        _Float16*       hwr = hbuf + 16 * HS;
        half8 ha[4];
        #pragma unroll
        for (int c = 0; c < 4; ++c)
            ha[c] = *(const half8*)&hrd[mrow * HS + c * 32 + quad * 8];
        f32x4 ar = { c_r0, c_r0, c_r0, c_r0 };
        f32x4 az = { c_z0, c_z0, c_z0, c_z0 };
        f32x4 aghn = { b_ngh, b_ngh, b_ngh, b_ngh };
        #pragma unroll
        for (int c = 0; c < 4; ++c) {
            ar   = __builtin_amdgcn_mfma_f32_16x16x32_f16(ha[c], wh[0][c], ar, 0, 0, 0);
            az   = __builtin_amdgcn_mfma_f32_16x16x32_f16(ha[c], wh[1][c], az, 0, 0, 0);
            aghn = __builtin_amdgcn_mfma_f32_16x16x32_f16(ha[c], wh[2][c], aghn, 0, 0, 0);
        }
        f32x4 agin = { c_n0, c_n0, c_n0, c_n0 };
        epilogue(ar, az, agin, aghn, hwr);
    }
    __syncthreads();

    // Step C: fold W2 = dWih*linW. r/z: wh <- fp16(dWhh + W2) (fp32 sum).
    // n: wxn <- fp16(W2). Three explicit rounds, constant frag indices.
    {
        const int kk = ((wv & 1) << 6) | ln;      // 0..127, lane's W2 column
        float lc[X_DIM];
        #pragma unroll
        for (int m = 0; m < X_DIM; ++m) lc[m] = linW[m * H_DIM + kk];
        const int jb = (wv >> 1) * 32;            // 4 wave-pairs x 32 rows

        // ---- gate 0 (r): combined ----
        #pragma unroll 1
        for (int jj = 0; jj < 32; ++jj) {
            const int j = __builtin_amdgcn_readfirstlane(jb + jj);
            const float* dwr = dWih + (size_t)j * X_DIM;
            float s = dWhh[(size_t)j * H_DIM + kk];
            #pragma unroll
            for (int m = 0; m < X_DIM; ++m) s += dwr[m] * lc[m];
            w2lds[j * H_DIM + kk] = (_Float16)s;
        }
        __syncthreads();
        #pragma unroll
        for (int c = 0; c < 4; ++c)
            wh[0][c] = *(const half8*)&w2lds[(wv * 16 + mrow) * H_DIM + c * 32 + quad * 8];
        __syncthreads();

        // ---- gate 1 (z): combined ----
        #pragma unroll 1
        for (int jj = 0; jj < 32; ++jj) {
            const int j = __builtin_amdgcn_readfirstlane(jb + jj);
            const float* dwr = dWih + (size_t)(H_DIM + j) * X_DIM;
            float s = dWhh[(size_t)(H_DIM + j) * H_DIM + kk];
            #pragma unroll
            for (int m = 0; m < X_DIM; ++m) s += dwr[m] * lc[m];
            w2lds[j * H_DIM + kk] = (_Float16)s;
        }
        __syncthreads();
        #pragma unroll
        for (int c = 0; c < 4; ++c)
            wh[1][c] = *(const half8*)&w2lds[(wv * 16 + mrow) * H_DIM + c * 32 + quad * 8];
        __syncthreads();

        // ---- gate 2 (n): W2 only (wh[2] stays pure dWhh) ----
        #pragma unroll 1
        for (int jj = 0; jj < 32; ++jj) {
            const int j = __builtin_amdgcn_readfirstlane(jb + jj);
            const float* dwr = dWih + (size_t)(2 * H_DIM + j) * X_DIM;
            float s = 0.0f;
            #pragma unroll
            for (int m = 0; m < X_DIM; ++m) s += dwr[m] * lc[m];
            w2lds[j * H_DIM + kk] = (_Float16)s;
        }
        __syncthreads();
        #pragma unroll
        for (int c = 0; c < 4; ++c)
            wxn[c] = *(const half8*)&w2lds[(wv * 16 + mrow) * H_DIM + c * 32 + quad * 8];
        __syncthreads();
    }

    // Step D: linear head frags + folded biases for t>=1.
    float lb = 0.0f;
    {
        const int n  = wv * 16 + mrow;
        const bool nv = (wv < 3) && (n < X_DIM);
        const float* lr = linW + (size_t)(nv ? n : 0) * H_DIM;
        #pragma unroll
        for (int c = 0; c < 4; ++c) {
            const int kb = c * 32 + quad * 8;
            half8 v;
            #pragma unroll
            for (int e = 0; e < 8; ++e)
                v[e] = nv ? (_Float16)lr[kb + e] : (_Float16)0.0f;
            wl[c] = v;
        }
        if (nv) lb = linb[n];
    }
    {
        float bf[3];
        #pragma unroll
        for (int p = 0; p < 3; ++p) {
            const float* dwr = dWih + (size_t)jcol[p] * X_DIM;
            float s = 0.0f;
            #pragma unroll
            for (int m = 0; m < X_DIM; ++m) s += linb[m] * dwr[m];
            bf[p] = s;
        }
        b_r  = c_r0 + bf[0];
        b_z  = c_z0 + bf[1];
        b_ngi = c_n0 + bf[2];
    }

    // ================= decoder (t=1..127, 1 barrier/step) =================
    #pragma unroll 1
    for (int t = 1; t < T_SEQ; ++t) {
        const _Float16* hrd = hbuf + (t & 1) * (16 * HS);
        _Float16*       hwr = hbuf + ((t & 1) ^ 1) * (16 * HS);

        half8 ha[4];
        #pragma unroll
        for (int c = 0; c < 4; ++c)
            ha[c] = *(const half8*)&hrd[mrow * HS + c * 32 + quad * 8];

        f32x4 ar = { b_r, b_r, b_r, b_r };
        #pragma unroll
        for (int c = 0; c < 4; ++c)
            ar = __builtin_amdgcn_mfma_f32_16x16x32_f16(ha[c], wh[0][c], ar, 0, 0, 0);
        f32x4 az = { b_z, b_z, b_z, b_z };
        #pragma unroll
        for (int c = 0; c < 4; ++c)
            az = __builtin_amdgcn_mfma_f32_16x16x32_f16(ha[c], wh[1][c], az, 0, 0, 0);
        f32x4 aghn = { b_ngh, b_ngh, b_ngh, b_ngh };
        #pragma unroll
        for (int c = 0; c < 4; ++c)
            aghn = __builtin_amdgcn_mfma_f32_16x16x32_f16(ha[c], wh[2][c], aghn, 0, 0, 0);
        f32x4 agin = { b_ngi, b_ngi, b_ngi, b_ngi };
        #pragma unroll
        for (int c = 0; c < 4; ++c)
            agin = __builtin_amdgcn_mfma_f32_16x16x32_f16(ha[c], wxn[c], agin, 0, 0, 0);

        // overlapped output projection: o_{t-1} = d_t @ linW^T + lb
        if (wv < 3) {
            f32x4 al = { lb, lb, lb, lb };
            #pragma unroll
            for (int c = 0; c < 4; ++c)
                al = __builtin_amdgcn_mfma_f32_16x16x32_f16(ha[c], wl[c], al, 0, 0, 0);
            const int n = wv * 16 + mrow;
            if (lower && n < X_DIM) {
                #pragma unroll
                for (int i = 0; i < 4; ++i)
                    out[((size_t)(b0 + quad * 4 + i) * T_SEQ + (t - 1)) * X_DIM + n] = al[i];
            }
        }

        epilogue(ar, az, agin, aghn, hwr);
        __syncthreads();
    }

    // tail projection: o_{T-1} = d_T @ linW^T + lb (d_128 is in hbuf[0])
    if (wv < 3) {
        const _Float16* hrd = hbuf;
        half8 ha[4];
        #pragma unroll
        for (int c = 0; c < 4; ++c)
            ha[c] = *(const half8*)&hrd[mrow * HS + c * 32 + quad * 8];
        f32x4 al = { lb, lb, lb, lb };
        #pragma unroll
        for (int c = 0; c < 4; ++c)
            al = __builtin_amdgcn_mfma_f32_16x16x32_f16(ha[c], wl[c], al, 0, 0, 0);
        const int n = wv * 16 + mrow;
        if (lower && n < X_DIM) {
            #pragma unroll
            for (int i = 0; i < 4; ++i)
                out[((size_t)(b0 + quad * 4 + i) * T_SEQ + (T_SEQ - 1)) * X_DIM + n] = al[i];
        }
    }
}

extern "C" void kernel_launch(void* const* d_in, const int* in_sizes, int n_in,
                              void* d_out, int out_size, void* d_ws, size_t ws_size,
                              hipStream_t stream) {
    (void)in_sizes; (void)n_in; (void)d_ws; (void)ws_size; (void)out_size;
    const float* x    = (const float*)d_in[0];
    const float* eWih = (const float*)d_in[1];
    const float* eWhh = (const float*)d_in[2];
    const float* ebih = (const float*)d_in[3];
    const float* ebhh = (const float*)d_in[4];
    const float* dWih = (const float*)d_in[5];
    const float* dWhh = (const float*)d_in[6];
    const float* dbih = (const float*)d_in[7];
    const float* dbhh = (const float*)d_in[8];
    const float* linW = (const float*)d_in[9];
    const float* linb = (const float*)d_in[10];
    float* out = (float*)d_out;

    rae_gru_kernel<<<dim3(B_TOT / BT), dim3(512), 0, stream>>>(
        x, eWih, eWhh, ebih, ebhh, dWih, dWhh, dbih, dbhh, linW, linb, out);
}